// Round 4
// baseline (691.895 us; speedup 1.0000x reference)
//
#include <hip/hip_runtime.h>

#define B_ 1024
#define N_ 256
#define C_ 128
#define L_ 4

typedef __bf16 bf16x8 __attribute__((ext_vector_type(8)));
typedef float f32x4 __attribute__((ext_vector_type(4)));

__device__ __forceinline__ float b2f(unsigned short u) {
    union { unsigned int i; float f; } v; v.i = ((unsigned int)u) << 16; return v.f;
}
__device__ __forceinline__ unsigned short f2b(float f) {
    union { float f; unsigned int i; } v; v.f = f;
    unsigned int u = v.i;
    u = (u + 0x7FFFu + ((u >> 16) & 1u)) >> 16;
    return (unsigned short)u;
}

// ---------------------------------------------------------------------------
// Kernel 0: prep (bf16):
//   wtp[br][0][d][c] = (W0 - W2 + I)[c][d]   (identity folded: out = x' + cheb)
//   wtp[br][1][d][c] = W1[c][d]
//   wtp[br][2][d][c] = 2*W2[c][d]
//   adj_bs = bf16(adj)
// ---------------------------------------------------------------------------
extern "C" __global__ __launch_bounds__(256) void k_prep(
    const float* __restrict__ Wt,
    const float* __restrict__ Wf,
    const float* __restrict__ adjf,
    unsigned short* __restrict__ wtp,
    unsigned short* __restrict__ adj_bs)
{
    int i = blockIdx.x * 256 + threadIdx.x;      // [0, 163840)
    if (i < 98304) {
        int br = i / 49152;
        int r  = i - br * 49152;
        int mat = r >> 14;
        int r2  = r & 16383;
        int d = r2 >> 7, c = r2 & 127;
        const float* S = br ? Wf : Wt;
        float v;
        if (mat == 0) {
            v = S[c * 128 + d] - S[2 * 16384 + c * 128 + d] + (c == d ? 1.0f : 0.0f);
        } else if (mat == 1) {
            v = S[16384 + c * 128 + d];
        } else {
            v = 2.0f * S[2 * 16384 + c * 128 + d];
        }
        wtp[i] = f2b(v);
    } else {
        int j = i - 98304;                        // [0, 65536)
        adj_bs[j] = f2b(adjf[j]);
    }
}

// ---------------------------------------------------------------------------
// Kernel 1: latent attention. fused[b][l][c] (f32), 512 threads/block.
// LDS: concat bf16 128KB (swizzled) + scr 8KB + part 4KB + lat 2KB = 142KB.
// ---------------------------------------------------------------------------
extern "C" __global__ __launch_bounds__(512) void k_latent(
    const float* __restrict__ timep,
    const float* __restrict__ frep,
    const float* __restrict__ latents,
    float* __restrict__ fused_out)
{
    extern __shared__ char smem[];
    float* scr  = (float*)(smem + 131072);            // [4][512] scores
    float* part = (float*)(smem + 131072 + 8192);     // [4][2][128] partials
    float* lat  = (float*)(smem + 131072 + 12288);    // [4][128]
    const int t = threadIdx.x;
    const int b = blockIdx.x;
    const float4* tg = (const float4*)(timep + (size_t)b * (N_ * C_));  // 8192 chunks
    const float4* fg = (const float4*)(frep  + (size_t)b * (N_ * C_));
#pragma unroll
    for (int i = 0; i < 32; ++i) {
        int ch = i * 512 + t;                     // [0,16384)
        const float4* p = (ch < 8192) ? (tg + ch) : (fg + (ch - 8192));
        float4 u = *p;
        int row = ch >> 5, c4 = ch & 31;
        unsigned short o[4] __attribute__((aligned(8)));
        o[0] = f2b(u.x); o[1] = f2b(u.y); o[2] = f2b(u.z); o[3] = f2b(u.w);
        *(uint2*)(smem + row * 256 + ((c4 * 8) ^ ((row & 7) << 4))) = *(const uint2*)o;
    }
    lat[t & 511] = latents[t & 511];
    __syncthreads();

    const float isc = 0.0883883476483184f;   // 1/sqrt(128)
    {   // scores: one row per thread
        const int jj = t;
        float s0 = 0, s1 = 0, s2 = 0, s3 = 0;
#pragma unroll
        for (int ci = 0; ci < 16; ++ci) {
            uint4 u = *(const uint4*)(smem + jj * 256 + ((ci * 16) ^ ((jj & 7) << 4)));
            const unsigned short* xb = (const unsigned short*)&u;
#pragma unroll
            for (int i = 0; i < 8; ++i) {
                float xv = b2f(xb[i]); int c = ci * 8 + i;
                s0 += xv * lat[c];           s1 += xv * lat[C_ + c];
                s2 += xv * lat[2 * C_ + c];  s3 += xv * lat[3 * C_ + c];
            }
        }
        scr[jj] = s0 * isc; scr[512 + jj] = s1 * isc;
        scr[1024 + jj] = s2 * isc; scr[1536 + jj] = s3 * isc;
    }
    __syncthreads();

    const int w = t >> 6, lane = t & 63;
    if (w < 4) {   // softmax over 512, wave w owns latent l=w
        float v[8]; float m = -1e30f;
#pragma unroll
        for (int i = 0; i < 8; ++i) { v[i] = scr[w * 512 + lane * 8 + i]; m = fmaxf(m, v[i]); }
#pragma unroll
        for (int off = 32; off >= 1; off >>= 1) m = fmaxf(m, __shfl_xor(m, off));
        float s = 0;
#pragma unroll
        for (int i = 0; i < 8; ++i) { v[i] = __expf(v[i] - m); s += v[i]; }
#pragma unroll
        for (int off = 32; off >= 1; off >>= 1) s += __shfl_xor(s, off);
        float inv = 1.0f / s;
#pragma unroll
        for (int i = 0; i < 8; ++i) scr[w * 512 + lane * 8 + i] = v[i] * inv;
    }
    __syncthreads();
    {   // weighted sum: wave w: latent l=w>>1, j-half = w&1; lane owns 2 channels
        const int l = w >> 1, jh = w & 1;
        float f0 = 0.f, f1 = 0.f;
        for (int j = jh * 256; j < jh * 256 + 256; ++j) {
            float p = scr[l * 512 + j];
            unsigned int pr = *(const unsigned int*)(smem + j * 256 + ((lane * 4) ^ ((j & 7) << 4)));
            f0 += p * b2f((unsigned short)(pr & 0xFFFFu));
            f1 += p * b2f((unsigned short)(pr >> 16));
        }
        part[(l * 2 + jh) * 128 + lane * 2]     = f0;
        part[(l * 2 + jh) * 128 + lane * 2 + 1] = f1;
    }
    __syncthreads();
    {
        int l = t >> 7, c = t & 127;
        fused_out[(size_t)b * 512 + l * 128 + c] =
            part[(l * 2) * 128 + c] + part[(l * 2 + 1) * 128 + c];
    }
}

// ---------------------------------------------------------------------------
// Kernel 2: per (batch, branch), 1024 threads (16 waves):
//   x' = x + scale*softmax(x·fused/sqrtC)@fused            (P1 -> xs)
//   outT  = b + (W0-W2+I)T·x'T        = acc_out            (G1a)
//   Y1T   = W1T·x'T                   = acc_z              (G1b)
//   Y2T   = (2W2)T·x'T                -> LDS (region B)    (G1c)
//   ZT    = Y1T + Y2T·adj             = acc_z -> region B  (G2)
//   outT += ZT·adj                                          (G3)
// LDS: xs[256][128]bf16 @0 (64K, swz ^((n&7)<<4))
//      Y2T/ZT [128][512B] @64K (64K, swz ^((c&7)<<4)), fused @128K (2K)
// Wave grid for [128c][256n]: wr=w>>3 (c 64-band), wc=w&7 (n 32-band), 4x2 frags.
// ---------------------------------------------------------------------------
extern "C" __global__ __launch_bounds__(1024, 4) void k_main(
    const float* __restrict__ timep,
    const float* __restrict__ frep,
    const unsigned short* __restrict__ adj,       // bf16 [256][256]
    const float* __restrict__ fused_ws,
    const float* __restrict__ scale_tp,
    const float* __restrict__ scale_fp,
    const unsigned short* __restrict__ wtp,
    const float* __restrict__ btp,
    const float* __restrict__ bfp,
    float* __restrict__ outp)
{
    extern __shared__ char smem[];
    float* fused_s = (float*)(smem + 131072);
    const int t  = threadIdx.x;
    const int b  = blockIdx.x;
    const int br = blockIdx.y;
    const float* xg = (br ? frep : timep) + (size_t)b * (N_ * C_);
    const unsigned short* wt0 = wtp + br * (3 * C_ * C_);
    const unsigned short* wt1 = wt0 + C_ * C_;
    const unsigned short* wt2 = wt0 + 2 * C_ * C_;
    const float* bias = br ? bfp : btp;
    float* og = outp + (size_t)br * B_ * N_ * C_ + (size_t)b * (N_ * C_);
    const float scale = (br ? scale_fp : scale_tp)[0];

    if (t < 512) fused_s[t] = fused_ws[(size_t)b * (L_ * C_) + t];
    __syncthreads();

    // ---- P1: x' -> xs (row-major, swizzled). thread: row n=t>>2, quarter q=t&3
    {
        const int n = t >> 2, q = t & 3;
        float xv[32];
        const float4* xr = (const float4*)(xg + n * C_ + q * 32);
#pragma unroll
        for (int i4 = 0; i4 < 8; ++i4) {
            float4 u = xr[i4];
            xv[i4 * 4 + 0] = u.x; xv[i4 * 4 + 1] = u.y;
            xv[i4 * 4 + 2] = u.z; xv[i4 * 4 + 3] = u.w;
        }
        float s0 = 0, s1 = 0, s2 = 0, s3 = 0;
#pragma unroll
        for (int k = 0; k < 32; ++k) {
            int c = q * 32 + k; float x = xv[k];
            s0 += x * fused_s[c];          s1 += x * fused_s[C_ + c];
            s2 += x * fused_s[2 * C_ + c]; s3 += x * fused_s[3 * C_ + c];
        }
        s0 += __shfl_xor(s0, 1); s1 += __shfl_xor(s1, 1);
        s2 += __shfl_xor(s2, 1); s3 += __shfl_xor(s3, 1);
        s0 += __shfl_xor(s0, 2); s1 += __shfl_xor(s1, 2);
        s2 += __shfl_xor(s2, 2); s3 += __shfl_xor(s3, 2);
        const float isc = 0.0883883476483184f;
        s0 *= isc; s1 *= isc; s2 *= isc; s3 *= isc;
        float m = fmaxf(fmaxf(s0, s1), fmaxf(s2, s3));
        float p0 = __expf(s0 - m), p1 = __expf(s1 - m), p2 = __expf(s2 - m), p3 = __expf(s3 - m);
        float inv = scale / (p0 + p1 + p2 + p3);
        p0 *= inv; p1 *= inv; p2 *= inv; p3 *= inv;
#pragma unroll
        for (int ci = 0; ci < 4; ++ci) {
            unsigned short ov[8] __attribute__((aligned(16)));
#pragma unroll
            for (int i = 0; i < 8; ++i) {
                int k = ci * 8 + i; int c = q * 32 + k;
                float v = xv[k] + p0 * fused_s[c] + p1 * fused_s[C_ + c]
                        + p2 * fused_s[2 * C_ + c] + p3 * fused_s[3 * C_ + c];
                ov[i] = f2b(v);
            }
            int chunk = q * 4 + ci;   // 16B chunk within row
            *(uint4*)(smem + n * 256 + ((chunk * 16) ^ ((n & 7) << 4))) = *(const uint4*)ov;
        }
    }
    __syncthreads();

    const int w = t >> 6, lane = t & 63;
    const int wr = w >> 3, wc = w & 7;          // c-band 64, n-band 32
    const int lr = lane & 15, lq = lane >> 4;

    // ---- G1: three K=128 passes sharing B-frags (B = xs rows n, k=c contig)
    f32x4 acc_out[4][2];   // outT frags: rows c, cols n
    f32x4 acc_z[4][2];     // Y1T -> ZT
    f32x4 tmp[4][2];       // Y2T
#pragma unroll
    for (int fm = 0; fm < 4; ++fm) {
        float4 b4 = *(const float4*)(bias + wr * 64 + fm * 16 + lq * 4);
#pragma unroll
        for (int fn = 0; fn < 2; ++fn) {
            acc_out[fm][fn] = f32x4{b4.x, b4.y, b4.z, b4.w};
            acc_z[fm][fn]   = f32x4{0.f, 0.f, 0.f, 0.f};
            tmp[fm][fn]     = f32x4{0.f, 0.f, 0.f, 0.f};
        }
    }
#pragma unroll
    for (int kk = 0; kk < 4; ++kk) {
        bf16x8 bfr[2];
#pragma unroll
        for (int fn = 0; fn < 2; ++fn) {
            int n = wc * 32 + fn * 16 + lr;
            bfr[fn] = __builtin_bit_cast(bf16x8,
                *(const uint4*)(smem + n * 256 + ((kk * 64 + lq * 16) ^ ((n & 7) << 4))));
        }
#pragma unroll
        for (int fm = 0; fm < 4; ++fm) {
            int d = wr * 64 + fm * 16 + lr;
            int ko = kk * 32 + lq * 8;
            bf16x8 a0 = __builtin_bit_cast(bf16x8, *(const uint4*)(wt0 + d * C_ + ko));
            bf16x8 a1 = __builtin_bit_cast(bf16x8, *(const uint4*)(wt1 + d * C_ + ko));
            bf16x8 a2 = __builtin_bit_cast(bf16x8, *(const uint4*)(wt2 + d * C_ + ko));
#pragma unroll
            for (int fn = 0; fn < 2; ++fn) {
                acc_out[fm][fn] = __builtin_amdgcn_mfma_f32_16x16x32_bf16(a0, bfr[fn], acc_out[fm][fn], 0, 0, 0);
                acc_z[fm][fn]   = __builtin_amdgcn_mfma_f32_16x16x32_bf16(a1, bfr[fn], acc_z[fm][fn],   0, 0, 0);
                tmp[fm][fn]     = __builtin_amdgcn_mfma_f32_16x16x32_bf16(a2, bfr[fn], tmp[fm][fn],     0, 0, 0);
            }
        }
    }
    __syncthreads();
    // write Y2T -> region B [c][n], row 512B, swizzled
#pragma unroll
    for (int fm = 0; fm < 4; ++fm)
#pragma unroll
        for (int fn = 0; fn < 2; ++fn) {
            int n = wc * 32 + fn * 16 + lr;
            f32x4 a = tmp[fm][fn];
#pragma unroll
            for (int r = 0; r < 4; ++r) {
                int c = wr * 64 + fm * 16 + lq * 4 + r;
                *(unsigned short*)(smem + 65536 + c * 512 + ((n * 2) ^ ((c & 7) << 4))) = f2b(a[r]);
            }
        }
    __syncthreads();

    // ---- G2: acc_z += Y2T · adj   [K=256]
#pragma unroll
    for (int kk = 0; kk < 8; ++kk) {
        bf16x8 afr[4], bfr[2];
#pragma unroll
        for (int fm = 0; fm < 4; ++fm) {
            int c = wr * 64 + fm * 16 + lr;
            afr[fm] = __builtin_bit_cast(bf16x8,
                *(const uint4*)(smem + 65536 + c * 512 + ((kk * 64 + lq * 16) ^ ((c & 7) << 4))));
        }
#pragma unroll
        for (int fn = 0; fn < 2; ++fn) {
            int n = wc * 32 + fn * 16 + lr;
            bfr[fn] = __builtin_bit_cast(bf16x8, *(const uint4*)(adj + n * N_ + kk * 32 + lq * 8));
        }
#pragma unroll
        for (int fm = 0; fm < 4; ++fm)
#pragma unroll
            for (int fn = 0; fn < 2; ++fn)
                acc_z[fm][fn] = __builtin_amdgcn_mfma_f32_16x16x32_bf16(afr[fm], bfr[fn], acc_z[fm][fn], 0, 0, 0);
    }
    __syncthreads();
    // write ZT over region B
#pragma unroll
    for (int fm = 0; fm < 4; ++fm)
#pragma unroll
        for (int fn = 0; fn < 2; ++fn) {
            int n = wc * 32 + fn * 16 + lr;
            f32x4 a = acc_z[fm][fn];
#pragma unroll
            for (int r = 0; r < 4; ++r) {
                int c = wr * 64 + fm * 16 + lq * 4 + r;
                *(unsigned short*)(smem + 65536 + c * 512 + ((n * 2) ^ ((c & 7) << 4))) = f2b(a[r]);
            }
        }
    __syncthreads();

    // ---- G3: acc_out += ZT · adj   [K=256]
#pragma unroll
    for (int kk = 0; kk < 8; ++kk) {
        bf16x8 afr[4], bfr[2];
#pragma unroll
        for (int fm = 0; fm < 4; ++fm) {
            int c = wr * 64 + fm * 16 + lr;
            afr[fm] = __builtin_bit_cast(bf16x8,
                *(const uint4*)(smem + 65536 + c * 512 + ((kk * 64 + lq * 16) ^ ((c & 7) << 4))));
        }
#pragma unroll
        for (int fn = 0; fn < 2; ++fn) {
            int n = wc * 32 + fn * 16 + lr;
            bfr[fn] = __builtin_bit_cast(bf16x8, *(const uint4*)(adj + n * N_ + kk * 32 + lq * 8));
        }
#pragma unroll
        for (int fm = 0; fm < 4; ++fm)
#pragma unroll
            for (int fn = 0; fn < 2; ++fn)
                acc_out[fm][fn] = __builtin_amdgcn_mfma_f32_16x16x32_bf16(afr[fm], bfr[fn], acc_out[fm][fn], 0, 0, 0);
    }

    // ---- store: outT frag = 4 consecutive channels at one n -> float4
#pragma unroll
    for (int fm = 0; fm < 4; ++fm) {
        int c0 = wr * 64 + fm * 16 + lq * 4;
#pragma unroll
        for (int fn = 0; fn < 2; ++fn) {
            int n = wc * 32 + fn * 16 + lr;
            *(float4*)(og + n * C_ + c0) = __builtin_bit_cast(float4, acc_out[fm][fn]);
        }
    }
}

// ---------------------------------------------------------------------------
extern "C" void kernel_launch(void* const* d_in, const int* in_sizes, int n_in,
                              void* d_out, int out_size, void* d_ws, size_t ws_size,
                              hipStream_t stream)
{
    const float* timep = (const float*)d_in[0];
    const float* frep  = (const float*)d_in[1];
    const float* adjf  = (const float*)d_in[2];
    const float* lat   = (const float*)d_in[3];
    const float* sct   = (const float*)d_in[4];
    const float* scf   = (const float*)d_in[5];
    const float* Wt    = (const float*)d_in[6];
    const float* bt    = (const float*)d_in[7];
    const float* Wf    = (const float*)d_in[8];
    const float* bf    = (const float*)d_in[9];
    float* outp = (float*)d_out;

    float* fused_ws = (float*)d_ws;                                     // 2 MB
    unsigned short* wtp    = (unsigned short*)((char*)d_ws + 2097152);  // 192 KB
    unsigned short* adj_bs = (unsigned short*)((char*)d_ws + 2097152 + 196608); // 128 KB

    hipFuncSetAttribute((const void*)k_latent, hipFuncAttributeMaxDynamicSharedMemorySize, 145408);
    hipFuncSetAttribute((const void*)k_main,   hipFuncAttributeMaxDynamicSharedMemorySize, 133120);

    k_prep<<<640, 256, 0, stream>>>(Wt, Wf, adjf, wtp, adj_bs);
    k_latent<<<1024, 512, 145408, stream>>>(timep, frep, lat, fused_ws);
    k_main<<<dim3(1024, 2), 1024, 133120, stream>>>(timep, frep, adj_bs, fused_ws,
                                                    sct, scf, wtp, bt, bf, outp);
}

// Round 5
// 558.119 us; speedup vs baseline: 1.2397x; 1.2397x over previous
//
#include <hip/hip_runtime.h>

#define B_ 1024
#define N_ 256
#define C_ 128
#define L_ 4

typedef __bf16 bf16x8 __attribute__((ext_vector_type(8)));
typedef float f32x4 __attribute__((ext_vector_type(4)));

__device__ __forceinline__ float b2f(unsigned short u) {
    union { unsigned int i; float f; } v; v.i = ((unsigned int)u) << 16; return v.f;
}
__device__ __forceinline__ unsigned short f2b(float f) {
    union { float f; unsigned int i; } v; v.f = f;
    unsigned int u = v.i;
    u = (u + 0x7FFFu + ((u >> 16) & 1u)) >> 16;
    return (unsigned short)u;
}

// ---------------------------------------------------------------------------
// Kernel 0: prep (bf16):
//   wtp[br][0][d][c] = (W0 - W2 + I)[c][d]
//   wtp[br][1][d][c] = W1[c][d]
//   wtp[br][2][d][c] = 2*W2[c][d]
//   adj_bs = bf16(adj)
// ---------------------------------------------------------------------------
extern "C" __global__ __launch_bounds__(256) void k_prep(
    const float* __restrict__ Wt,
    const float* __restrict__ Wf,
    const float* __restrict__ adjf,
    unsigned short* __restrict__ wtp,
    unsigned short* __restrict__ adj_bs)
{
    int i = blockIdx.x * 256 + threadIdx.x;      // [0, 163840)
    if (i < 98304) {
        int br = i / 49152;
        int r  = i - br * 49152;
        int mat = r >> 14;
        int r2  = r & 16383;
        int d = r2 >> 7, c = r2 & 127;
        const float* S = br ? Wf : Wt;
        float v;
        if (mat == 0) {
            v = S[c * 128 + d] - S[2 * 16384 + c * 128 + d] + (c == d ? 1.0f : 0.0f);
        } else if (mat == 1) {
            v = S[16384 + c * 128 + d];
        } else {
            v = 2.0f * S[2 * 16384 + c * 128 + d];
        }
        wtp[i] = f2b(v);
    } else {
        int j = i - 98304;                        // [0, 65536)
        adj_bs[j] = f2b(adjf[j]);
    }
}

// ---------------------------------------------------------------------------
// Kernel 1: latent attention. fused[b][l][c] (f32), 512 threads/block.
// ---------------------------------------------------------------------------
extern "C" __global__ __launch_bounds__(512) void k_latent(
    const float* __restrict__ timep,
    const float* __restrict__ frep,
    const float* __restrict__ latents,
    float* __restrict__ fused_out)
{
    extern __shared__ char smem[];
    float* scr  = (float*)(smem + 131072);            // [4][512] scores
    float* part = (float*)(smem + 131072 + 8192);     // [4][2][128] partials
    float* lat  = (float*)(smem + 131072 + 12288);    // [4][128]
    const int t = threadIdx.x;
    const int b = blockIdx.x;
    const float4* tg = (const float4*)(timep + (size_t)b * (N_ * C_));
    const float4* fg = (const float4*)(frep  + (size_t)b * (N_ * C_));
#pragma unroll
    for (int i = 0; i < 32; ++i) {
        int ch = i * 512 + t;                     // [0,16384)
        const float4* p = (ch < 8192) ? (tg + ch) : (fg + (ch - 8192));
        float4 u = *p;
        int row = ch >> 5, c4 = ch & 31;
        unsigned short o[4] __attribute__((aligned(8)));
        o[0] = f2b(u.x); o[1] = f2b(u.y); o[2] = f2b(u.z); o[3] = f2b(u.w);
        *(uint2*)(smem + row * 256 + ((c4 * 8) ^ ((row & 7) << 4))) = *(const uint2*)o;
    }
    lat[t & 511] = latents[t & 511];
    __syncthreads();

    const float isc = 0.0883883476483184f;   // 1/sqrt(128)
    {   // scores: one row per thread
        const int jj = t;
        float s0 = 0, s1 = 0, s2 = 0, s3 = 0;
#pragma unroll
        for (int ci = 0; ci < 16; ++ci) {
            uint4 u = *(const uint4*)(smem + jj * 256 + ((ci * 16) ^ ((jj & 7) << 4)));
            const unsigned short* xb = (const unsigned short*)&u;
#pragma unroll
            for (int i = 0; i < 8; ++i) {
                float xv = b2f(xb[i]); int c = ci * 8 + i;
                s0 += xv * lat[c];           s1 += xv * lat[C_ + c];
                s2 += xv * lat[2 * C_ + c];  s3 += xv * lat[3 * C_ + c];
            }
        }
        scr[jj] = s0 * isc; scr[512 + jj] = s1 * isc;
        scr[1024 + jj] = s2 * isc; scr[1536 + jj] = s3 * isc;
    }
    __syncthreads();

    const int w = t >> 6, lane = t & 63;
    if (w < 4) {   // softmax over 512, wave w owns latent l=w
        float v[8]; float m = -1e30f;
#pragma unroll
        for (int i = 0; i < 8; ++i) { v[i] = scr[w * 512 + lane * 8 + i]; m = fmaxf(m, v[i]); }
#pragma unroll
        for (int off = 32; off >= 1; off >>= 1) m = fmaxf(m, __shfl_xor(m, off));
        float s = 0;
#pragma unroll
        for (int i = 0; i < 8; ++i) { v[i] = __expf(v[i] - m); s += v[i]; }
#pragma unroll
        for (int off = 32; off >= 1; off >>= 1) s += __shfl_xor(s, off);
        float inv = 1.0f / s;
#pragma unroll
        for (int i = 0; i < 8; ++i) scr[w * 512 + lane * 8 + i] = v[i] * inv;
    }
    __syncthreads();
    {   // weighted sum: wave w: latent l=w>>1, half jh=w&1; lane owns 2 channels
        const int l = w >> 1, jh = w & 1;
        float f0 = 0.f, f1 = 0.f;
        for (int j = jh * 256; j < jh * 256 + 256; ++j) {
            float p = scr[l * 512 + j];
            unsigned int pr = *(const unsigned int*)(smem + j * 256 + ((lane * 4) ^ ((j & 7) << 4)));
            f0 += p * b2f((unsigned short)(pr & 0xFFFFu));
            f1 += p * b2f((unsigned short)(pr >> 16));
        }
        part[(l * 2 + jh) * 128 + lane * 2]     = f0;
        part[(l * 2 + jh) * 128 + lane * 2 + 1] = f1;
    }
    __syncthreads();
    {
        int l = t >> 7, c = t & 127;
        fused_out[(size_t)b * 512 + l * 128 + c] =
            part[(l * 2) * 128 + c] + part[(l * 2 + 1) * 128 + c];
    }
}

// ---------------------------------------------------------------------------
// Kernel 2: per (batch, branch), 1024 threads (16 waves).
//   out = x'(W0-W2+I) + adj·(x'W1 + adj·(x'·2W2)) + b, with x' = cross-attn.
// Phases (adj symmetric => outT via ZT·adj):
//   P1 : x' -> xs (region A, [256n][128c] bf16, swz ^((n&7)<<4))
//   G1c: Y2 = xs·(2W2)      D[n][c] -> packed 8B write Y2T (region B [c][512B])
//   G1b: acc = xs·W1        D[n][c]
//   G2 : acc += adj·Y2      (A=adj global rows, B=Y2T LDS) -> packed write ZT
//   G1a: accO = b + W0''T·xsT   D[c][n]  (A=wtp0 global, B=xs rows)
//   G3 : accO += ZT·adj         D[c][n]  (A=ZT LDS, B=adj global rows)
//   store: float4 (4 consecutive c at one n)
// ---------------------------------------------------------------------------
extern "C" __global__ __launch_bounds__(1024, 1) void k_main(
    const float* __restrict__ timep,
    const float* __restrict__ frep,
    const unsigned short* __restrict__ adj,       // bf16 [256][256], symmetric
    const float* __restrict__ fused_ws,
    const float* __restrict__ scale_tp,
    const float* __restrict__ scale_fp,
    const unsigned short* __restrict__ wtp,
    const float* __restrict__ btp,
    const float* __restrict__ bfp,
    float* __restrict__ outp)
{
    extern __shared__ char smem[];
    float* fused_s = (float*)(smem + 131072);
    const int t  = threadIdx.x;
    const int b  = blockIdx.x;
    const int br = blockIdx.y;
    const float* xg = (br ? frep : timep) + (size_t)b * (N_ * C_);
    const unsigned short* wt0 = wtp + br * (3 * C_ * C_);
    const unsigned short* wt1 = wt0 + C_ * C_;
    const unsigned short* wt2 = wt0 + 2 * C_ * C_;
    const float* bias = br ? bfp : btp;
    float* og = outp + (size_t)br * B_ * N_ * C_ + (size_t)b * (N_ * C_);
    const float scale = (br ? scale_fp : scale_tp)[0];

    if (t < 512) fused_s[t] = fused_ws[(size_t)b * (L_ * C_) + t];
    __syncthreads();

    // ---- P1: x' -> xs. thread: row n=t>>2, quarter q=t&3
    {
        const int n = t >> 2, q = t & 3;
        float xv[32];
        const float4* xr = (const float4*)(xg + n * C_ + q * 32);
#pragma unroll
        for (int i4 = 0; i4 < 8; ++i4) {
            float4 u = xr[i4];
            xv[i4 * 4 + 0] = u.x; xv[i4 * 4 + 1] = u.y;
            xv[i4 * 4 + 2] = u.z; xv[i4 * 4 + 3] = u.w;
        }
        float s0 = 0, s1 = 0, s2 = 0, s3 = 0;
#pragma unroll
        for (int k = 0; k < 32; ++k) {
            int c = q * 32 + k; float x = xv[k];
            s0 += x * fused_s[c];          s1 += x * fused_s[C_ + c];
            s2 += x * fused_s[2 * C_ + c]; s3 += x * fused_s[3 * C_ + c];
        }
        s0 += __shfl_xor(s0, 1); s1 += __shfl_xor(s1, 1);
        s2 += __shfl_xor(s2, 1); s3 += __shfl_xor(s3, 1);
        s0 += __shfl_xor(s0, 2); s1 += __shfl_xor(s1, 2);
        s2 += __shfl_xor(s2, 2); s3 += __shfl_xor(s3, 2);
        const float isc = 0.0883883476483184f;
        s0 *= isc; s1 *= isc; s2 *= isc; s3 *= isc;
        float m = fmaxf(fmaxf(s0, s1), fmaxf(s2, s3));
        float p0 = __expf(s0 - m), p1 = __expf(s1 - m), p2 = __expf(s2 - m), p3 = __expf(s3 - m);
        float inv = scale / (p0 + p1 + p2 + p3);
        p0 *= inv; p1 *= inv; p2 *= inv; p3 *= inv;
#pragma unroll
        for (int ci = 0; ci < 4; ++ci) {
            unsigned short ov[8] __attribute__((aligned(16)));
#pragma unroll
            for (int i = 0; i < 8; ++i) {
                int k = ci * 8 + i; int c = q * 32 + k;
                float v = xv[k] + p0 * fused_s[c] + p1 * fused_s[C_ + c]
                        + p2 * fused_s[2 * C_ + c] + p3 * fused_s[3 * C_ + c];
                ov[i] = f2b(v);
            }
            int chunk = q * 4 + ci;
            *(uint4*)(smem + n * 256 + ((chunk * 16) ^ ((n & 7) << 4))) = *(const uint4*)ov;
        }
    }
    __syncthreads();

    const int w = t >> 6, lane = t & 63;
    const int lr = lane & 15, lq = lane >> 4;
    // non-T wave grid: [256n][128c]: wrn = n-band of 64, wcc = c-band of 32
    const int wrn = w >> 2, wcc = w & 3;
    // T wave grid: [128c][256n]: wr = c-band of 64, wc = n-band of 32
    const int wr = w >> 3, wc = w & 7;

    // ---- G1c: Y2 = xs·(2W2)  [K=128], D[n][c]
    {
        f32x4 acc2[4][2];
#pragma unroll
        for (int fm = 0; fm < 4; ++fm)
#pragma unroll
            for (int fn = 0; fn < 2; ++fn) acc2[fm][fn] = f32x4{0.f, 0.f, 0.f, 0.f};
#pragma unroll
        for (int kk = 0; kk < 4; ++kk) {
            bf16x8 afr[4], bfr[2];
#pragma unroll
            for (int fm = 0; fm < 4; ++fm) {
                int n = wrn * 64 + fm * 16 + lr;
                afr[fm] = __builtin_bit_cast(bf16x8,
                    *(const uint4*)(smem + n * 256 + ((kk * 64 + lq * 16) ^ ((n & 7) << 4))));
            }
#pragma unroll
            for (int fn = 0; fn < 2; ++fn) {
                int c = wcc * 32 + fn * 16 + lr;
                bfr[fn] = __builtin_bit_cast(bf16x8, *(const uint4*)(wt2 + c * C_ + kk * 32 + lq * 8));
            }
#pragma unroll
            for (int fm = 0; fm < 4; ++fm)
#pragma unroll
                for (int fn = 0; fn < 2; ++fn)
                    acc2[fm][fn] = __builtin_amdgcn_mfma_f32_16x16x32_bf16(afr[fm], bfr[fn], acc2[fm][fn], 0, 0, 0);
        }
        // packed write Y2T[c][n]: 4 consecutive n (8B) at row c
#pragma unroll
        for (int fm = 0; fm < 4; ++fm)
#pragma unroll
            for (int fn = 0; fn < 2; ++fn) {
                int c  = wcc * 32 + fn * 16 + lr;
                int n0 = wrn * 64 + fm * 16 + lq * 4;
                f32x4 a = acc2[fm][fn];
                unsigned short tmp[4] __attribute__((aligned(8)));
#pragma unroll
                for (int r = 0; r < 4; ++r) tmp[r] = f2b(a[r]);
                *(uint2*)(smem + 65536 + c * 512 + ((n0 * 2) ^ ((c & 7) << 4))) = *(const uint2*)tmp;
            }
    }
    __syncthreads();

    // ---- G1b + G2: acc = xs·W1 + adj·Y2   [K=128 then K=256], D[n][c]
    {
        f32x4 acc[4][2];
#pragma unroll
        for (int fm = 0; fm < 4; ++fm)
#pragma unroll
            for (int fn = 0; fn < 2; ++fn) acc[fm][fn] = f32x4{0.f, 0.f, 0.f, 0.f};
#pragma unroll
        for (int kk = 0; kk < 4; ++kk) {
            bf16x8 afr[4], bfr[2];
#pragma unroll
            for (int fm = 0; fm < 4; ++fm) {
                int n = wrn * 64 + fm * 16 + lr;
                afr[fm] = __builtin_bit_cast(bf16x8,
                    *(const uint4*)(smem + n * 256 + ((kk * 64 + lq * 16) ^ ((n & 7) << 4))));
            }
#pragma unroll
            for (int fn = 0; fn < 2; ++fn) {
                int c = wcc * 32 + fn * 16 + lr;
                bfr[fn] = __builtin_bit_cast(bf16x8, *(const uint4*)(wt1 + c * C_ + kk * 32 + lq * 8));
            }
#pragma unroll
            for (int fm = 0; fm < 4; ++fm)
#pragma unroll
                for (int fn = 0; fn < 2; ++fn)
                    acc[fm][fn] = __builtin_amdgcn_mfma_f32_16x16x32_bf16(afr[fm], bfr[fn], acc[fm][fn], 0, 0, 0);
        }
        // G2: acc += adj·Y2  (A = adj rows n global; B = Y2T rows c LDS)
#pragma unroll
        for (int kk = 0; kk < 8; ++kk) {
            bf16x8 afr[4], bfr[2];
#pragma unroll
            for (int fm = 0; fm < 4; ++fm) {
                int n = wrn * 64 + fm * 16 + lr;
                afr[fm] = __builtin_bit_cast(bf16x8, *(const uint4*)(adj + n * N_ + kk * 32 + lq * 8));
            }
#pragma unroll
            for (int fn = 0; fn < 2; ++fn) {
                int c = wcc * 32 + fn * 16 + lr;
                bfr[fn] = __builtin_bit_cast(bf16x8,
                    *(const uint4*)(smem + 65536 + c * 512 + ((kk * 64 + lq * 16) ^ ((c & 7) << 4))));
            }
#pragma unroll
            for (int fm = 0; fm < 4; ++fm)
#pragma unroll
                for (int fn = 0; fn < 2; ++fn)
                    acc[fm][fn] = __builtin_amdgcn_mfma_f32_16x16x32_bf16(afr[fm], bfr[fn], acc[fm][fn], 0, 0, 0);
        }
        __syncthreads();   // all G2 reads of Y2T done
        // packed write ZT[c][n] over region B
#pragma unroll
        for (int fm = 0; fm < 4; ++fm)
#pragma unroll
            for (int fn = 0; fn < 2; ++fn) {
                int c  = wcc * 32 + fn * 16 + lr;
                int n0 = wrn * 64 + fm * 16 + lq * 4;
                f32x4 a = acc[fm][fn];
                unsigned short tmp[4] __attribute__((aligned(8)));
#pragma unroll
                for (int r = 0; r < 4; ++r) tmp[r] = f2b(a[r]);
                *(uint2*)(smem + 65536 + c * 512 + ((n0 * 2) ^ ((c & 7) << 4))) = *(const uint2*)tmp;
            }
    }

    // ---- G1a: accO = bias + W0''T·xsT  [K=128], D[c][n]  (no region-B dep)
    f32x4 accO[4][2];
#pragma unroll
    for (int fm = 0; fm < 4; ++fm) {
        float4 b4 = *(const float4*)(bias + wr * 64 + fm * 16 + lq * 4);
#pragma unroll
        for (int fn = 0; fn < 2; ++fn) accO[fm][fn] = f32x4{b4.x, b4.y, b4.z, b4.w};
    }
#pragma unroll
    for (int kk = 0; kk < 4; ++kk) {
        bf16x8 afr[4], bfr[2];
#pragma unroll
        for (int fm = 0; fm < 4; ++fm) {
            int d = wr * 64 + fm * 16 + lr;
            afr[fm] = __builtin_bit_cast(bf16x8, *(const uint4*)(wt0 + d * C_ + kk * 32 + lq * 8));
        }
#pragma unroll
        for (int fn = 0; fn < 2; ++fn) {
            int n = wc * 32 + fn * 16 + lr;
            bfr[fn] = __builtin_bit_cast(bf16x8,
                *(const uint4*)(smem + n * 256 + ((kk * 64 + lq * 16) ^ ((n & 7) << 4))));
        }
#pragma unroll
        for (int fm = 0; fm < 4; ++fm)
#pragma unroll
            for (int fn = 0; fn < 2; ++fn)
                accO[fm][fn] = __builtin_amdgcn_mfma_f32_16x16x32_bf16(afr[fm], bfr[fn], accO[fm][fn], 0, 0, 0);
    }
    __syncthreads();   // ZT writes visible

    // ---- G3: accO += ZT·adj  [K=256], D[c][n]
#pragma unroll
    for (int kk = 0; kk < 8; ++kk) {
        bf16x8 afr[4], bfr[2];
#pragma unroll
        for (int fm = 0; fm < 4; ++fm) {
            int c = wr * 64 + fm * 16 + lr;
            afr[fm] = __builtin_bit_cast(bf16x8,
                *(const uint4*)(smem + 65536 + c * 512 + ((kk * 64 + lq * 16) ^ ((c & 7) << 4))));
        }
#pragma unroll
        for (int fn = 0; fn < 2; ++fn) {
            int n = wc * 32 + fn * 16 + lr;
            bfr[fn] = __builtin_bit_cast(bf16x8, *(const uint4*)(adj + n * N_ + kk * 32 + lq * 8));
        }
#pragma unroll
        for (int fm = 0; fm < 4; ++fm)
#pragma unroll
            for (int fn = 0; fn < 2; ++fn)
                accO[fm][fn] = __builtin_amdgcn_mfma_f32_16x16x32_bf16(afr[fm], bfr[fn], accO[fm][fn], 0, 0, 0);
    }

    // ---- store: D[c][n] frag = 4 consecutive c at one n -> float4
#pragma unroll
    for (int fm = 0; fm < 4; ++fm) {
        int c0 = wr * 64 + fm * 16 + lq * 4;
#pragma unroll
        for (int fn = 0; fn < 2; ++fn) {
            int n = wc * 32 + fn * 16 + lr;
            *(float4*)(og + n * C_ + c0) = __builtin_bit_cast(float4, accO[fm][fn]);
        }
    }
}

// ---------------------------------------------------------------------------
extern "C" void kernel_launch(void* const* d_in, const int* in_sizes, int n_in,
                              void* d_out, int out_size, void* d_ws, size_t ws_size,
                              hipStream_t stream)
{
    const float* timep = (const float*)d_in[0];
    const float* frep  = (const float*)d_in[1];
    const float* adjf  = (const float*)d_in[2];
    const float* lat   = (const float*)d_in[3];
    const float* sct   = (const float*)d_in[4];
    const float* scf   = (const float*)d_in[5];
    const float* Wt    = (const float*)d_in[6];
    const float* bt    = (const float*)d_in[7];
    const float* Wf    = (const float*)d_in[8];
    const float* bf    = (const float*)d_in[9];
    float* outp = (float*)d_out;

    float* fused_ws = (float*)d_ws;                                     // 2 MB
    unsigned short* wtp    = (unsigned short*)((char*)d_ws + 2097152);  // 192 KB
    unsigned short* adj_bs = (unsigned short*)((char*)d_ws + 2097152 + 196608); // 128 KB

    hipFuncSetAttribute((const void*)k_latent, hipFuncAttributeMaxDynamicSharedMemorySize, 145408);
    hipFuncSetAttribute((const void*)k_main,   hipFuncAttributeMaxDynamicSharedMemorySize, 133120);

    k_prep<<<640, 256, 0, stream>>>(Wt, Wf, adjf, wtp, adj_bs);
    k_latent<<<1024, 512, 145408, stream>>>(timep, frep, lat, fused_ws);
    k_main<<<dim3(1024, 2), 1024, 133120, stream>>>(timep, frep, adj_bs, fused_ws,
                                                    sct, scf, wtp, bt, bf, outp);
}

// Round 6
// 552.762 us; speedup vs baseline: 1.2517x; 1.0097x over previous
//
#include <hip/hip_runtime.h>

#define B_ 1024
#define N_ 256
#define C_ 128
#define L_ 4

typedef __bf16 bf16x8 __attribute__((ext_vector_type(8)));
typedef float f32x4 __attribute__((ext_vector_type(4)));

__device__ __forceinline__ float b2f(unsigned short u) {
    union { unsigned int i; float f; } v; v.i = ((unsigned int)u) << 16; return v.f;
}
__device__ __forceinline__ unsigned short f2b(float f) {
    union { float f; unsigned int i; } v; v.f = f;
    unsigned int u = v.i;
    u = (u + 0x7FFFu + ((u >> 16) & 1u)) >> 16;
    return (unsigned short)u;
}

// ---------------------------------------------------------------------------
// Kernel 0: prep (bf16):
//   wtp[br][0][d][c] = (W0 - W2 + I)[c][d]
//   wtp[br][1][d][c] = W1[c][d]
//   wtp[br][2][d][c] = 2*W2[c][d]
//   adj_bs = bf16(adj)
// ---------------------------------------------------------------------------
extern "C" __global__ __launch_bounds__(256) void k_prep(
    const float* __restrict__ Wt,
    const float* __restrict__ Wf,
    const float* __restrict__ adjf,
    unsigned short* __restrict__ wtp,
    unsigned short* __restrict__ adj_bs)
{
    int i = blockIdx.x * 256 + threadIdx.x;      // [0, 163840)
    if (i < 98304) {
        int br = i / 49152;
        int r  = i - br * 49152;
        int mat = r >> 14;
        int r2  = r & 16383;
        int d = r2 >> 7, c = r2 & 127;
        const float* S = br ? Wf : Wt;
        float v;
        if (mat == 0) {
            v = S[c * 128 + d] - S[2 * 16384 + c * 128 + d] + (c == d ? 1.0f : 0.0f);
        } else if (mat == 1) {
            v = S[16384 + c * 128 + d];
        } else {
            v = 2.0f * S[2 * 16384 + c * 128 + d];
        }
        wtp[i] = f2b(v);
    } else {
        int j = i - 98304;                        // [0, 65536)
        adj_bs[j] = f2b(adjf[j]);
    }
}

// ---------------------------------------------------------------------------
// Kernel 1: latent attention. fused[b][l][c] (f32), 512 threads/block.
// ---------------------------------------------------------------------------
extern "C" __global__ __launch_bounds__(512) void k_latent(
    const float* __restrict__ timep,
    const float* __restrict__ frep,
    const float* __restrict__ latents,
    float* __restrict__ fused_out)
{
    extern __shared__ char smem[];
    float* scr  = (float*)(smem + 131072);            // [4][512] scores
    float* part = (float*)(smem + 131072 + 8192);     // [4][2][128] partials
    float* lat  = (float*)(smem + 131072 + 12288);    // [4][128]
    const int t = threadIdx.x;
    const int b = blockIdx.x;
    const float4* tg = (const float4*)(timep + (size_t)b * (N_ * C_));
    const float4* fg = (const float4*)(frep  + (size_t)b * (N_ * C_));
#pragma unroll
    for (int i = 0; i < 32; ++i) {
        int ch = i * 512 + t;                     // [0,16384)
        const float4* p = (ch < 8192) ? (tg + ch) : (fg + (ch - 8192));
        float4 u = *p;
        int row = ch >> 5, c4 = ch & 31;
        unsigned short o[4] __attribute__((aligned(8)));
        o[0] = f2b(u.x); o[1] = f2b(u.y); o[2] = f2b(u.z); o[3] = f2b(u.w);
        *(uint2*)(smem + row * 256 + ((c4 * 8) ^ ((row & 7) << 4))) = *(const uint2*)o;
    }
    lat[t & 511] = latents[t & 511];
    __syncthreads();

    const float isc = 0.0883883476483184f;   // 1/sqrt(128)
    {   // scores: one row per thread
        const int jj = t;
        float s0 = 0, s1 = 0, s2 = 0, s3 = 0;
#pragma unroll
        for (int ci = 0; ci < 16; ++ci) {
            uint4 u = *(const uint4*)(smem + jj * 256 + ((ci * 16) ^ ((jj & 7) << 4)));
            const unsigned short* xb = (const unsigned short*)&u;
#pragma unroll
            for (int i = 0; i < 8; ++i) {
                float xv = b2f(xb[i]); int c = ci * 8 + i;
                s0 += xv * lat[c];           s1 += xv * lat[C_ + c];
                s2 += xv * lat[2 * C_ + c];  s3 += xv * lat[3 * C_ + c];
            }
        }
        scr[jj] = s0 * isc; scr[512 + jj] = s1 * isc;
        scr[1024 + jj] = s2 * isc; scr[1536 + jj] = s3 * isc;
    }
    __syncthreads();

    const int w = t >> 6, lane = t & 63;
    if (w < 4) {   // softmax over 512, wave w owns latent l=w
        float v[8]; float m = -1e30f;
#pragma unroll
        for (int i = 0; i < 8; ++i) { v[i] = scr[w * 512 + lane * 8 + i]; m = fmaxf(m, v[i]); }
#pragma unroll
        for (int off = 32; off >= 1; off >>= 1) m = fmaxf(m, __shfl_xor(m, off));
        float s = 0;
#pragma unroll
        for (int i = 0; i < 8; ++i) { v[i] = __expf(v[i] - m); s += v[i]; }
#pragma unroll
        for (int off = 32; off >= 1; off >>= 1) s += __shfl_xor(s, off);
        float inv = 1.0f / s;
#pragma unroll
        for (int i = 0; i < 8; ++i) scr[w * 512 + lane * 8 + i] = v[i] * inv;
    }
    __syncthreads();
    {   // weighted sum: wave w: latent l=w>>1, half jh=w&1; lane owns 2 channels
        const int l = w >> 1, jh = w & 1;
        float f0 = 0.f, f1 = 0.f;
        for (int j = jh * 256; j < jh * 256 + 256; ++j) {
            float p = scr[l * 512 + j];
            unsigned int pr = *(const unsigned int*)(smem + j * 256 + ((lane * 4) ^ ((j & 7) << 4)));
            f0 += p * b2f((unsigned short)(pr & 0xFFFFu));
            f1 += p * b2f((unsigned short)(pr >> 16));
        }
        part[(l * 2 + jh) * 128 + lane * 2]     = f0;
        part[(l * 2 + jh) * 128 + lane * 2 + 1] = f1;
    }
    __syncthreads();
    {
        int l = t >> 7, c = t & 127;
        fused_out[(size_t)b * 512 + l * 128 + c] =
            part[(l * 2) * 128 + c] + part[(l * 2 + 1) * 128 + c];
    }
}

// ---------------------------------------------------------------------------
// Kernel 2: per (batch, branch), 512 threads (8 waves), LDS 80KB -> 2 blocks/CU.
//   out = x'(W0-W2+I) + adj·(x'W1 + adj·(x'·2W2)) + b
// LDS: xs [256n][256B] @0 (64KB, swz ^((n&7)<<4))
//      chunk buf @64K (16KB): fused_s (P1 only) / Y2T chunk / ZT chunk
//        chunk layout [128c][128B] rows, swz ^((c&7)<<4), n-chunk of 64
// Phases:
//   P1   x' -> xs
//   G1b  acc  = xs·W1                       (wave [64n][64c], fm4 fn4 kk4)
//   x4:  G1c chunk: Y2c = xs[band]·2W2 -> buf; G2: acc += adj[:,band]·Y2c
//   cvt  Zb = bf16(acc)  (32 regs)
//   G1a  accO = b + W0''T·xsT               (T-grid: wave [64c][64n])
//   x4:  owners write ZTc from Zb; G3: accO += ZTc·adj[band,:]
//   store float4
// ---------------------------------------------------------------------------
extern "C" __global__ __launch_bounds__(512, 2) void k_main(
    const float* __restrict__ timep,
    const float* __restrict__ frep,
    const unsigned short* __restrict__ adj,       // bf16 [256][256], symmetric
    const float* __restrict__ fused_ws,
    const float* __restrict__ scale_tp,
    const float* __restrict__ scale_fp,
    const unsigned short* __restrict__ wtp,
    const float* __restrict__ btp,
    const float* __restrict__ bfp,
    float* __restrict__ outp)
{
    extern __shared__ char smem[];
    char* cb = smem + 65536;                 // 16KB chunk region
    float* fused_s = (float*)cb;             // alias, valid through P1 only
    const int t  = threadIdx.x;
    const int b  = blockIdx.x;
    const int br = blockIdx.y;
    const float* xg = (br ? frep : timep) + (size_t)b * (N_ * C_);
    const unsigned short* wt0 = wtp + br * (3 * C_ * C_);
    const unsigned short* wt1 = wt0 + C_ * C_;
    const unsigned short* wt2 = wt0 + 2 * C_ * C_;
    const float* bias = br ? bfp : btp;
    float* og = outp + (size_t)br * B_ * N_ * C_ + (size_t)b * (N_ * C_);
    const float scale = (br ? scale_fp : scale_tp)[0];

    fused_s[t] = fused_ws[(size_t)b * (L_ * C_) + t];
    __syncthreads();

    // ---- P1: x' -> xs. thread: row n=t>>1, half h=t&1 (64 channels)
    {
        const int n = t >> 1, h = t & 1;
        float xv[64];
        const float4* xr = (const float4*)(xg + n * C_ + h * 64);
#pragma unroll
        for (int i4 = 0; i4 < 16; ++i4) {
            float4 u = xr[i4];
            xv[i4 * 4 + 0] = u.x; xv[i4 * 4 + 1] = u.y;
            xv[i4 * 4 + 2] = u.z; xv[i4 * 4 + 3] = u.w;
        }
        float s0 = 0, s1 = 0, s2 = 0, s3 = 0;
#pragma unroll
        for (int k = 0; k < 64; ++k) {
            int c = h * 64 + k; float x = xv[k];
            s0 += x * fused_s[c];          s1 += x * fused_s[C_ + c];
            s2 += x * fused_s[2 * C_ + c]; s3 += x * fused_s[3 * C_ + c];
        }
        s0 += __shfl_xor(s0, 1); s1 += __shfl_xor(s1, 1);
        s2 += __shfl_xor(s2, 1); s3 += __shfl_xor(s3, 1);
        const float isc = 0.0883883476483184f;
        s0 *= isc; s1 *= isc; s2 *= isc; s3 *= isc;
        float m = fmaxf(fmaxf(s0, s1), fmaxf(s2, s3));
        float p0 = __expf(s0 - m), p1 = __expf(s1 - m), p2 = __expf(s2 - m), p3 = __expf(s3 - m);
        float inv = scale / (p0 + p1 + p2 + p3);
        p0 *= inv; p1 *= inv; p2 *= inv; p3 *= inv;
#pragma unroll
        for (int ci = 0; ci < 8; ++ci) {
            unsigned short ov[8] __attribute__((aligned(16)));
#pragma unroll
            for (int i = 0; i < 8; ++i) {
                int k = ci * 8 + i; int c = h * 64 + k;
                float v = xv[k] + p0 * fused_s[c] + p1 * fused_s[C_ + c]
                        + p2 * fused_s[2 * C_ + c] + p3 * fused_s[3 * C_ + c];
                ov[i] = f2b(v);
            }
            int chunk = h * 8 + ci;
            *(uint4*)(smem + n * 256 + ((chunk * 16) ^ ((n & 7) << 4))) = *(const uint4*)ov;
        }
    }
    __syncthreads();   // xs visible; fused_s dead -> chunk buf free

    const int w = t >> 6, lane = t & 63;
    const int lr = lane & 15, lq = lane >> 4;
    const int wrn = w >> 1, wcc = w & 1;     // D[n][c]: n-band 64, c-band 64
    const int wct = w >> 2, wnt = w & 3;     // D[c][n]: c-band 64, n-band 64
    const int rn  = w >> 1;                  // G1c: n-subband 16 within chunk

    // ---- G1b: acc = xs·W1   [K=128], D[n][c]
    f32x4 acc[4][4];
#pragma unroll
    for (int fm = 0; fm < 4; ++fm)
#pragma unroll
        for (int fn = 0; fn < 4; ++fn) acc[fm][fn] = f32x4{0.f, 0.f, 0.f, 0.f};
#pragma unroll
    for (int kk = 0; kk < 4; ++kk) {
        bf16x8 afr[4], bfr[4];
#pragma unroll
        for (int fm = 0; fm < 4; ++fm) {
            int n = wrn * 64 + fm * 16 + lr;
            afr[fm] = __builtin_bit_cast(bf16x8,
                *(const uint4*)(smem + n * 256 + ((kk * 64 + lq * 16) ^ ((n & 7) << 4))));
        }
#pragma unroll
        for (int fn = 0; fn < 4; ++fn) {
            int d = wcc * 64 + fn * 16 + lr;
            bfr[fn] = __builtin_bit_cast(bf16x8, *(const uint4*)(wt1 + d * C_ + kk * 32 + lq * 8));
        }
#pragma unroll
        for (int fm = 0; fm < 4; ++fm)
#pragma unroll
            for (int fn = 0; fn < 4; ++fn)
                acc[fm][fn] = __builtin_amdgcn_mfma_f32_16x16x32_bf16(afr[fm], bfr[fn], acc[fm][fn], 0, 0, 0);
    }

    // ---- chunk loop: Y2 chunk + G2 partial
    for (int ch = 0; ch < 4; ++ch) {
        // G1c: Y2c[16n sub][64c] per wave
        f32x4 acc2[4];
#pragma unroll
        for (int fn = 0; fn < 4; ++fn) acc2[fn] = f32x4{0.f, 0.f, 0.f, 0.f};
#pragma unroll
        for (int kk = 0; kk < 4; ++kk) {
            int n = ch * 64 + rn * 16 + lr;
            bf16x8 a = __builtin_bit_cast(bf16x8,
                *(const uint4*)(smem + n * 256 + ((kk * 64 + lq * 16) ^ ((n & 7) << 4))));
#pragma unroll
            for (int fn = 0; fn < 4; ++fn) {
                int d = wcc * 64 + fn * 16 + lr;
                bf16x8 bfr = __builtin_bit_cast(bf16x8, *(const uint4*)(wt2 + d * C_ + kk * 32 + lq * 8));
                acc2[fn] = __builtin_amdgcn_mfma_f32_16x16x32_bf16(a, bfr, acc2[fn], 0, 0, 0);
            }
        }
        // write Y2T chunk [128c][64n-local]
#pragma unroll
        for (int fn = 0; fn < 4; ++fn) {
            int c   = wcc * 64 + fn * 16 + lr;
            int n0l = rn * 16 + lq * 4;
            f32x4 a = acc2[fn];
            unsigned short tmp[4] __attribute__((aligned(8)));
#pragma unroll
            for (int r = 0; r < 4; ++r) tmp[r] = f2b(a[r]);
            *(uint2*)(cb + c * 128 + ((n0l * 2) ^ ((c & 7) << 4))) = *(const uint2*)tmp;
        }
        __syncthreads();
        // G2: acc += adj[:,chunk]·Y2c   [K=64]
#pragma unroll
        for (int kk = 0; kk < 2; ++kk) {
            bf16x8 afr[4], bfr[4];
#pragma unroll
            for (int fm = 0; fm < 4; ++fm) {
                int n = wrn * 64 + fm * 16 + lr;
                afr[fm] = __builtin_bit_cast(bf16x8,
                    *(const uint4*)(adj + n * N_ + ch * 64 + kk * 32 + lq * 8));
            }
#pragma unroll
            for (int fn = 0; fn < 4; ++fn) {
                int c = wcc * 64 + fn * 16 + lr;
                bfr[fn] = __builtin_bit_cast(bf16x8,
                    *(const uint4*)(cb + c * 128 + ((kk * 64 + lq * 16) ^ ((c & 7) << 4))));
            }
#pragma unroll
            for (int fm = 0; fm < 4; ++fm)
#pragma unroll
                for (int fn = 0; fn < 4; ++fn)
                    acc[fm][fn] = __builtin_amdgcn_mfma_f32_16x16x32_bf16(afr[fm], bfr[fn], acc[fm][fn], 0, 0, 0);
        }
        __syncthreads();   // G2 reads done before next chunk's writes
    }

    // ---- cvt Z -> bf16 packed (frees acc)
    uint2 Zb[4][4];
#pragma unroll
    for (int fm = 0; fm < 4; ++fm)
#pragma unroll
        for (int fn = 0; fn < 4; ++fn) {
            f32x4 a = acc[fm][fn];
            unsigned short tmp[4] __attribute__((aligned(8)));
#pragma unroll
            for (int r = 0; r < 4; ++r) tmp[r] = f2b(a[r]);
            Zb[fm][fn] = *(const uint2*)tmp;
        }

    // ---- G1a: accO = bias + W0''T·xsT  [K=128], D[c][n]
    f32x4 accO[4][4];
#pragma unroll
    for (int fm = 0; fm < 4; ++fm) {
        float4 b4 = *(const float4*)(bias + wct * 64 + fm * 16 + lq * 4);
#pragma unroll
        for (int fn = 0; fn < 4; ++fn) accO[fm][fn] = f32x4{b4.x, b4.y, b4.z, b4.w};
    }
#pragma unroll
    for (int kk = 0; kk < 4; ++kk) {
        bf16x8 afr[4], bfr[4];
#pragma unroll
        for (int fm = 0; fm < 4; ++fm) {
            int d = wct * 64 + fm * 16 + lr;
            afr[fm] = __builtin_bit_cast(bf16x8, *(const uint4*)(wt0 + d * C_ + kk * 32 + lq * 8));
        }
#pragma unroll
        for (int fn = 0; fn < 4; ++fn) {
            int n = wnt * 64 + fn * 16 + lr;
            bfr[fn] = __builtin_bit_cast(bf16x8,
                *(const uint4*)(smem + n * 256 + ((kk * 64 + lq * 16) ^ ((n & 7) << 4))));
        }
#pragma unroll
        for (int fm = 0; fm < 4; ++fm)
#pragma unroll
            for (int fn = 0; fn < 4; ++fn)
                accO[fm][fn] = __builtin_amdgcn_mfma_f32_16x16x32_bf16(afr[fm], bfr[fn], accO[fm][fn], 0, 0, 0);
    }

    // ---- ZT chunk loop + G3
    for (int ch = 0; ch < 4; ++ch) {
        if (wrn == ch) {   // owner waves (2) write ZT chunk [128c][64n-local]
#pragma unroll
            for (int fm = 0; fm < 4; ++fm)
#pragma unroll
                for (int fn = 0; fn < 4; ++fn) {
                    int c   = wcc * 64 + fn * 16 + lr;
                    int n0l = fm * 16 + lq * 4;
                    *(uint2*)(cb + c * 128 + ((n0l * 2) ^ ((c & 7) << 4))) = Zb[fm][fn];
                }
        }
        __syncthreads();
        // G3: accO += ZTc·adj[chunk,:]   [K=64]
#pragma unroll
        for (int kk = 0; kk < 2; ++kk) {
            bf16x8 afr[4], bfr[4];
#pragma unroll
            for (int fm = 0; fm < 4; ++fm) {
                int c = wct * 64 + fm * 16 + lr;
                afr[fm] = __builtin_bit_cast(bf16x8,
                    *(const uint4*)(cb + c * 128 + ((kk * 64 + lq * 16) ^ ((c & 7) << 4))));
            }
#pragma unroll
            for (int fn = 0; fn < 4; ++fn) {
                int n = wnt * 64 + fn * 16 + lr;
                bfr[fn] = __builtin_bit_cast(bf16x8,
                    *(const uint4*)(adj + n * N_ + ch * 64 + kk * 32 + lq * 8));
            }
#pragma unroll
            for (int fm = 0; fm < 4; ++fm)
#pragma unroll
                for (int fn = 0; fn < 4; ++fn)
                    accO[fm][fn] = __builtin_amdgcn_mfma_f32_16x16x32_bf16(afr[fm], bfr[fn], accO[fm][fn], 0, 0, 0);
        }
        __syncthreads();
    }

    // ---- store: D[c][n] frag = 4 consecutive c at one n -> float4
#pragma unroll
    for (int fm = 0; fm < 4; ++fm) {
        int c0 = wct * 64 + fm * 16 + lq * 4;
#pragma unroll
        for (int fn = 0; fn < 4; ++fn) {
            int n = wnt * 64 + fn * 16 + lr;
            *(float4*)(og + n * C_ + c0) = __builtin_bit_cast(float4, accO[fm][fn]);
        }
    }
}

// ---------------------------------------------------------------------------
extern "C" void kernel_launch(void* const* d_in, const int* in_sizes, int n_in,
                              void* d_out, int out_size, void* d_ws, size_t ws_size,
                              hipStream_t stream)
{
    const float* timep = (const float*)d_in[0];
    const float* frep  = (const float*)d_in[1];
    const float* adjf  = (const float*)d_in[2];
    const float* lat   = (const float*)d_in[3];
    const float* sct   = (const float*)d_in[4];
    const float* scf   = (const float*)d_in[5];
    const float* Wt    = (const float*)d_in[6];
    const float* bt    = (const float*)d_in[7];
    const float* Wf    = (const float*)d_in[8];
    const float* bf    = (const float*)d_in[9];
    float* outp = (float*)d_out;

    float* fused_ws = (float*)d_ws;                                     // 2 MB
    unsigned short* wtp    = (unsigned short*)((char*)d_ws + 2097152);  // 192 KB
    unsigned short* adj_bs = (unsigned short*)((char*)d_ws + 2097152 + 196608); // 128 KB

    hipFuncSetAttribute((const void*)k_latent, hipFuncAttributeMaxDynamicSharedMemorySize, 145408);
    hipFuncSetAttribute((const void*)k_main,   hipFuncAttributeMaxDynamicSharedMemorySize, 81920);

    k_prep<<<640, 256, 0, stream>>>(Wt, Wf, adjf, wtp, adj_bs);
    k_latent<<<1024, 512, 145408, stream>>>(timep, frep, lat, fused_ws);
    k_main<<<dim3(1024, 2), 512, 81920, stream>>>(timep, frep, adj_bs, fused_ws,
                                                  sct, scf, wtp, bt, bf, outp);
}

// Round 7
// 519.789 us; speedup vs baseline: 1.3311x; 1.0634x over previous
//
#include <hip/hip_runtime.h>

#define B_ 1024
#define N_ 256
#define C_ 128
#define L_ 4

typedef __bf16 bf16x8 __attribute__((ext_vector_type(8)));
typedef float f32x4 __attribute__((ext_vector_type(4)));

__device__ __forceinline__ float b2f(unsigned short u) {
    union { unsigned int i; float f; } v; v.i = ((unsigned int)u) << 16; return v.f;
}
__device__ __forceinline__ unsigned short f2b(float f) {
    union { float f; unsigned int i; } v; v.f = f;
    unsigned int u = v.i;
    u = (u + 0x7FFFu + ((u >> 16) & 1u)) >> 16;
    return (unsigned short)u;
}

// ---------------------------------------------------------------------------
// Kernel 0: prep (bf16): wtp[br][0]=(W0-W2+I)^T, [1]=W1^T, [2]=(2W2)^T; adj bf16
// ---------------------------------------------------------------------------
extern "C" __global__ __launch_bounds__(256) void k_prep(
    const float* __restrict__ Wt,
    const float* __restrict__ Wf,
    const float* __restrict__ adjf,
    unsigned short* __restrict__ wtp,
    unsigned short* __restrict__ adj_bs)
{
    int i = blockIdx.x * 256 + threadIdx.x;      // [0, 163840)
    if (i < 98304) {
        int br = i / 49152;
        int r  = i - br * 49152;
        int mat = r >> 14;
        int r2  = r & 16383;
        int d = r2 >> 7, c = r2 & 127;
        const float* S = br ? Wf : Wt;
        float v;
        if (mat == 0) {
            v = S[c * 128 + d] - S[2 * 16384 + c * 128 + d] + (c == d ? 1.0f : 0.0f);
        } else if (mat == 1) {
            v = S[16384 + c * 128 + d];
        } else {
            v = 2.0f * S[2 * 16384 + c * 128 + d];
        }
        wtp[i] = f2b(v);
    } else {
        int j = i - 98304;                        // [0, 65536)
        adj_bs[j] = f2b(adjf[j]);
    }
}

// ---------------------------------------------------------------------------
// Kernel 1: latent attention (+ optional x' production).
// 512 threads. LDS: concat bf16 128KB swz + scr 8KB + part 4KB + lat 2KB.
// If do_xp: after fused, compute x' rows in-place and write bf16 x' to ws:
//   xpws[(br*1024+b)*256 + n][c]
// ---------------------------------------------------------------------------
extern "C" __global__ __launch_bounds__(512) void k_latent(
    const float* __restrict__ timep,
    const float* __restrict__ frep,
    const float* __restrict__ latents,
    const float* __restrict__ scale_tp,
    const float* __restrict__ scale_fp,
    float* __restrict__ fused_out,
    unsigned short* __restrict__ xpws,
    int do_xp)
{
    extern __shared__ char smem[];
    float* scr  = (float*)(smem + 131072);            // [4][512] scores
    float* part = (float*)(smem + 131072 + 8192);     // [4][2][128] partials
    float* lat  = (float*)(smem + 131072 + 12288);    // [4][128] latents -> fused
    const int t = threadIdx.x;
    const int b = blockIdx.x;
    const float4* tg = (const float4*)(timep + (size_t)b * (N_ * C_));
    const float4* fg = (const float4*)(frep  + (size_t)b * (N_ * C_));
#pragma unroll
    for (int i = 0; i < 32; ++i) {
        int ch = i * 512 + t;                     // [0,16384)
        const float4* p = (ch < 8192) ? (tg + ch) : (fg + (ch - 8192));
        float4 u = *p;
        int row = ch >> 5, c4 = ch & 31;
        unsigned short o[4] __attribute__((aligned(8)));
        o[0] = f2b(u.x); o[1] = f2b(u.y); o[2] = f2b(u.z); o[3] = f2b(u.w);
        *(uint2*)(smem + row * 256 + ((c4 * 8) ^ ((row & 7) << 4))) = *(const uint2*)o;
    }
    lat[t & 511] = latents[t & 511];
    __syncthreads();

    const float isc = 0.0883883476483184f;   // 1/sqrt(128)
    {   // scores vs latents: one row per thread
        const int jj = t;
        float s0 = 0, s1 = 0, s2 = 0, s3 = 0;
#pragma unroll
        for (int ci = 0; ci < 16; ++ci) {
            uint4 u = *(const uint4*)(smem + jj * 256 + ((ci * 16) ^ ((jj & 7) << 4)));
            const unsigned short* xb = (const unsigned short*)&u;
#pragma unroll
            for (int i = 0; i < 8; ++i) {
                float xv = b2f(xb[i]); int c = ci * 8 + i;
                s0 += xv * lat[c];           s1 += xv * lat[C_ + c];
                s2 += xv * lat[2 * C_ + c];  s3 += xv * lat[3 * C_ + c];
            }
        }
        scr[jj] = s0 * isc; scr[512 + jj] = s1 * isc;
        scr[1024 + jj] = s2 * isc; scr[1536 + jj] = s3 * isc;
    }
    __syncthreads();

    const int w = t >> 6, lane = t & 63;
    if (w < 4) {   // softmax over 512, wave w owns latent l=w
        float v[8]; float m = -1e30f;
#pragma unroll
        for (int i = 0; i < 8; ++i) { v[i] = scr[w * 512 + lane * 8 + i]; m = fmaxf(m, v[i]); }
#pragma unroll
        for (int off = 32; off >= 1; off >>= 1) m = fmaxf(m, __shfl_xor(m, off));
        float s = 0;
#pragma unroll
        for (int i = 0; i < 8; ++i) { v[i] = __expf(v[i] - m); s += v[i]; }
#pragma unroll
        for (int off = 32; off >= 1; off >>= 1) s += __shfl_xor(s, off);
        float inv = 1.0f / s;
#pragma unroll
        for (int i = 0; i < 8; ++i) scr[w * 512 + lane * 8 + i] = v[i] * inv;
    }
    __syncthreads();
    {   // weighted sum: wave w: latent l=w>>1, half jh=w&1; lane owns 2 channels
        const int l = w >> 1, jh = w & 1;
        float f0 = 0.f, f1 = 0.f;
        for (int j = jh * 256; j < jh * 256 + 256; ++j) {
            float p = scr[l * 512 + j];
            unsigned int pr = *(const unsigned int*)(smem + j * 256 + ((lane * 4) ^ ((j & 7) << 4)));
            f0 += p * b2f((unsigned short)(pr & 0xFFFFu));
            f1 += p * b2f((unsigned short)(pr >> 16));
        }
        part[(l * 2 + jh) * 128 + lane * 2]     = f0;
        part[(l * 2 + jh) * 128 + lane * 2 + 1] = f1;
    }
    __syncthreads();
    {   // finalize fused -> lat (overwrites latents; dead) and to ws (fallback)
        int l = t >> 7, c = t & 127;
        float f = part[(l * 2) * 128 + c] + part[(l * 2 + 1) * 128 + c];
        lat[l * 128 + c] = f;
        fused_out[(size_t)b * 512 + l * 128 + c] = f;
    }
    __syncthreads();

    if (!do_xp) return;

    // ---- x' phase: thread owns row j; x' = x + scale*softmax(x·fused/√C)@fused
    {
        const int j = t;
        const int brx = j >> 8;
        const float scale = brx ? scale_fp[0] : scale_tp[0];
        float s0 = 0, s1 = 0, s2 = 0, s3 = 0;
#pragma unroll
        for (int ci = 0; ci < 16; ++ci) {
            uint4 u = *(const uint4*)(smem + j * 256 + ((ci * 16) ^ ((j & 7) << 4)));
            const unsigned short* xb = (const unsigned short*)&u;
#pragma unroll
            for (int i = 0; i < 8; ++i) {
                float xv = b2f(xb[i]); int c = ci * 8 + i;
                s0 += xv * lat[c];           s1 += xv * lat[C_ + c];
                s2 += xv * lat[2 * C_ + c];  s3 += xv * lat[3 * C_ + c];
            }
        }
        s0 *= isc; s1 *= isc; s2 *= isc; s3 *= isc;
        float m = fmaxf(fmaxf(s0, s1), fmaxf(s2, s3));
        float p0 = __expf(s0 - m), p1 = __expf(s1 - m), p2 = __expf(s2 - m), p3 = __expf(s3 - m);
        float inv = scale / (p0 + p1 + p2 + p3);
        p0 *= inv; p1 *= inv; p2 *= inv; p3 *= inv;
#pragma unroll
        for (int ci = 0; ci < 16; ++ci) {
            char* slot = smem + j * 256 + ((ci * 16) ^ ((j & 7) << 4));
            uint4 u = *(const uint4*)slot;
            const unsigned short* xb = (const unsigned short*)&u;
            unsigned short ov[8] __attribute__((aligned(16)));
#pragma unroll
            for (int i = 0; i < 8; ++i) {
                int c = ci * 8 + i;
                float v = b2f(xb[i]) + p0 * lat[c] + p1 * lat[C_ + c]
                        + p2 * lat[2 * C_ + c] + p3 * lat[3 * C_ + c];
                ov[i] = f2b(v);
            }
            *(uint4*)slot = *(const uint4*)ov;
        }
    }
    __syncthreads();

    // ---- coalesced copy-out: x'ws[(br*1024+b)*256 + n][c]
    {
#pragma unroll
        for (int i = 0; i < 16; ++i) {
            int ch = i * 512 + t;                 // 8192 chunks of 16B
            int row = ch >> 4, cj = ch & 15;
            uint4 u = *(const uint4*)(smem + row * 256 + ((cj * 16) ^ ((row & 7) << 4)));
            size_t off = (((size_t)(row >> 8) * B_ + b) * N_ + (row & 255)) * C_ + cj * 8;
            *(uint4*)(xpws + off) = u;
        }
    }
}

// ---------------------------------------------------------------------------
// Kernel 2 (fast): per (batch, branch), 512 threads, LDS 16KB -> 2 blocks/CU.
//   out = x'(W0-W2+I) + adj·(x'W1 + adj·(x'·2W2)) + b ; x' read from ws (bf16)
// LDS: chunk buf 16KB: Y2T/ZT chunks [128c][128B] rows swz ^((c&7)<<4)
// ---------------------------------------------------------------------------
extern "C" __global__ __launch_bounds__(512, 2) void k_cheb(
    const unsigned short* __restrict__ adj,       // bf16 [256][256], symmetric
    const unsigned short* __restrict__ wtp,
    const float* __restrict__ btp,
    const float* __restrict__ bfp,
    const unsigned short* __restrict__ xpws,
    float* __restrict__ outp)
{
    extern __shared__ char smem[];
    char* cb = smem;                          // 16KB chunk region
    const int t  = threadIdx.x;
    const int b  = blockIdx.x;
    const int br = blockIdx.y;
    const unsigned short* xw = xpws + (((size_t)br * B_ + b) * N_) * C_;
    const unsigned short* wt0 = wtp + br * (3 * C_ * C_);
    const unsigned short* wt1 = wt0 + C_ * C_;
    const unsigned short* wt2 = wt0 + 2 * C_ * C_;
    const float* bias = br ? bfp : btp;
    float* og = outp + (size_t)br * B_ * N_ * C_ + (size_t)b * (N_ * C_);

    const int w = t >> 6, lane = t & 63;
    const int lr = lane & 15, lq = lane >> 4;
    const int wrn = w >> 1, wcc = w & 1;     // D[n][c]: n-band 64, c-band 64
    const int wct = w >> 2, wnt = w & 3;     // D[c][n]: c-band 64, n-band 64
    const int rn  = w >> 1;                  // G1c: 16-row subband within chunk

    // ---- G1b: acc = x'·W1   [K=128], D[n][c]
    f32x4 acc[4][4];
#pragma unroll
    for (int fm = 0; fm < 4; ++fm)
#pragma unroll
        for (int fn = 0; fn < 4; ++fn) acc[fm][fn] = f32x4{0.f, 0.f, 0.f, 0.f};
#pragma unroll
    for (int kk = 0; kk < 4; ++kk) {
        bf16x8 afr[4], bfr[4];
#pragma unroll
        for (int fm = 0; fm < 4; ++fm) {
            int n = wrn * 64 + fm * 16 + lr;
            afr[fm] = __builtin_bit_cast(bf16x8, *(const uint4*)(xw + n * C_ + kk * 32 + lq * 8));
        }
#pragma unroll
        for (int fn = 0; fn < 4; ++fn) {
            int d = wcc * 64 + fn * 16 + lr;
            bfr[fn] = __builtin_bit_cast(bf16x8, *(const uint4*)(wt1 + d * C_ + kk * 32 + lq * 8));
        }
#pragma unroll
        for (int fm = 0; fm < 4; ++fm)
#pragma unroll
            for (int fn = 0; fn < 4; ++fn)
                acc[fm][fn] = __builtin_amdgcn_mfma_f32_16x16x32_bf16(afr[fm], bfr[fn], acc[fm][fn], 0, 0, 0);
    }

    // ---- chunk loop: Y2 chunk + G2 partial
    for (int ch = 0; ch < 4; ++ch) {
        f32x4 acc2[4];
#pragma unroll
        for (int fn = 0; fn < 4; ++fn) acc2[fn] = f32x4{0.f, 0.f, 0.f, 0.f};
#pragma unroll
        for (int kk = 0; kk < 4; ++kk) {
            int n = ch * 64 + rn * 16 + lr;
            bf16x8 a = __builtin_bit_cast(bf16x8, *(const uint4*)(xw + n * C_ + kk * 32 + lq * 8));
#pragma unroll
            for (int fn = 0; fn < 4; ++fn) {
                int d = wcc * 64 + fn * 16 + lr;
                bf16x8 bfr = __builtin_bit_cast(bf16x8, *(const uint4*)(wt2 + d * C_ + kk * 32 + lq * 8));
                acc2[fn] = __builtin_amdgcn_mfma_f32_16x16x32_bf16(a, bfr, acc2[fn], 0, 0, 0);
            }
        }
#pragma unroll
        for (int fn = 0; fn < 4; ++fn) {
            int c   = wcc * 64 + fn * 16 + lr;
            int n0l = rn * 16 + lq * 4;
            f32x4 a = acc2[fn];
            unsigned short tmp[4] __attribute__((aligned(8)));
#pragma unroll
            for (int r = 0; r < 4; ++r) tmp[r] = f2b(a[r]);
            *(uint2*)(cb + c * 128 + ((n0l * 2) ^ ((c & 7) << 4))) = *(const uint2*)tmp;
        }
        __syncthreads();
#pragma unroll
        for (int kk = 0; kk < 2; ++kk) {
            bf16x8 afr[4], bfr[4];
#pragma unroll
            for (int fm = 0; fm < 4; ++fm) {
                int n = wrn * 64 + fm * 16 + lr;
                afr[fm] = __builtin_bit_cast(bf16x8,
                    *(const uint4*)(adj + n * N_ + ch * 64 + kk * 32 + lq * 8));
            }
#pragma unroll
            for (int fn = 0; fn < 4; ++fn) {
                int c = wcc * 64 + fn * 16 + lr;
                bfr[fn] = __builtin_bit_cast(bf16x8,
                    *(const uint4*)(cb + c * 128 + ((kk * 64 + lq * 16) ^ ((c & 7) << 4))));
            }
#pragma unroll
            for (int fm = 0; fm < 4; ++fm)
#pragma unroll
                for (int fn = 0; fn < 4; ++fn)
                    acc[fm][fn] = __builtin_amdgcn_mfma_f32_16x16x32_bf16(afr[fm], bfr[fn], acc[fm][fn], 0, 0, 0);
        }
        __syncthreads();
    }

    // ---- cvt Z -> bf16 packed (frees acc)
    uint2 Zb[4][4];
#pragma unroll
    for (int fm = 0; fm < 4; ++fm)
#pragma unroll
        for (int fn = 0; fn < 4; ++fn) {
            f32x4 a = acc[fm][fn];
            unsigned short tmp[4] __attribute__((aligned(8)));
#pragma unroll
            for (int r = 0; r < 4; ++r) tmp[r] = f2b(a[r]);
            Zb[fm][fn] = *(const uint2*)tmp;
        }

    // ---- G1a: accO = bias + W0''T·x'T  [K=128], D[c][n]
    f32x4 accO[4][4];
#pragma unroll
    for (int fm = 0; fm < 4; ++fm) {
        float4 b4 = *(const float4*)(bias + wct * 64 + fm * 16 + lq * 4);
#pragma unroll
        for (int fn = 0; fn < 4; ++fn) accO[fm][fn] = f32x4{b4.x, b4.y, b4.z, b4.w};
    }
#pragma unroll
    for (int kk = 0; kk < 4; ++kk) {
        bf16x8 afr[4], bfr[4];
#pragma unroll
        for (int fm = 0; fm < 4; ++fm) {
            int d = wct * 64 + fm * 16 + lr;
            afr[fm] = __builtin_bit_cast(bf16x8, *(const uint4*)(wt0 + d * C_ + kk * 32 + lq * 8));
        }
#pragma unroll
        for (int fn = 0; fn < 4; ++fn) {
            int n = wnt * 64 + fn * 16 + lr;
            bfr[fn] = __builtin_bit_cast(bf16x8, *(const uint4*)(xw + n * C_ + kk * 32 + lq * 8));
        }
#pragma unroll
        for (int fm = 0; fm < 4; ++fm)
#pragma unroll
            for (int fn = 0; fn < 4; ++fn)
                accO[fm][fn] = __builtin_amdgcn_mfma_f32_16x16x32_bf16(afr[fm], bfr[fn], accO[fm][fn], 0, 0, 0);
    }
    __syncthreads();

    // ---- ZT chunk loop + G3
    for (int ch = 0; ch < 4; ++ch) {
        if (wrn == ch) {
#pragma unroll
            for (int fm = 0; fm < 4; ++fm)
#pragma unroll
                for (int fn = 0; fn < 4; ++fn) {
                    int c   = wcc * 64 + fn * 16 + lr;
                    int n0l = fm * 16 + lq * 4;
                    *(uint2*)(cb + c * 128 + ((n0l * 2) ^ ((c & 7) << 4))) = Zb[fm][fn];
                }
        }
        __syncthreads();
#pragma unroll
        for (int kk = 0; kk < 2; ++kk) {
            bf16x8 afr[4], bfr[4];
#pragma unroll
            for (int fm = 0; fm < 4; ++fm) {
                int c = wct * 64 + fm * 16 + lr;
                afr[fm] = __builtin_bit_cast(bf16x8,
                    *(const uint4*)(cb + c * 128 + ((kk * 64 + lq * 16) ^ ((c & 7) << 4))));
            }
#pragma unroll
            for (int fn = 0; fn < 4; ++fn) {
                int n = wnt * 64 + fn * 16 + lr;
                bfr[fn] = __builtin_bit_cast(bf16x8,
                    *(const uint4*)(adj + n * N_ + ch * 64 + kk * 32 + lq * 8));
            }
#pragma unroll
            for (int fm = 0; fm < 4; ++fm)
#pragma unroll
                for (int fn = 0; fn < 4; ++fn)
                    accO[fm][fn] = __builtin_amdgcn_mfma_f32_16x16x32_bf16(afr[fm], bfr[fn], accO[fm][fn], 0, 0, 0);
        }
        __syncthreads();
    }

    // ---- store: D[c][n] frag = 4 consecutive c at one n -> float4
#pragma unroll
    for (int fm = 0; fm < 4; ++fm) {
        int c0 = wct * 64 + fm * 16 + lq * 4;
#pragma unroll
        for (int fn = 0; fn < 4; ++fn) {
            int n = wnt * 64 + fn * 16 + lr;
            *(float4*)(og + n * C_ + c0) = __builtin_bit_cast(float4, accO[fm][fn]);
        }
    }
}

// ---------------------------------------------------------------------------
// Kernel 2 (fallback = round-6 k_main): used only if ws too small for x'.
// ---------------------------------------------------------------------------
extern "C" __global__ __launch_bounds__(512, 2) void k_main_fb(
    const float* __restrict__ timep,
    const float* __restrict__ frep,
    const unsigned short* __restrict__ adj,
    const float* __restrict__ fused_ws,
    const float* __restrict__ scale_tp,
    const float* __restrict__ scale_fp,
    const unsigned short* __restrict__ wtp,
    const float* __restrict__ btp,
    const float* __restrict__ bfp,
    float* __restrict__ outp)
{
    extern __shared__ char smem[];
    char* cb = smem + 65536;
    float* fused_s = (float*)cb;
    const int t  = threadIdx.x;
    const int b  = blockIdx.x;
    const int br = blockIdx.y;
    const float* xg = (br ? frep : timep) + (size_t)b * (N_ * C_);
    const unsigned short* wt0 = wtp + br * (3 * C_ * C_);
    const unsigned short* wt1 = wt0 + C_ * C_;
    const unsigned short* wt2 = wt0 + 2 * C_ * C_;
    const float* bias = br ? bfp : btp;
    float* og = outp + (size_t)br * B_ * N_ * C_ + (size_t)b * (N_ * C_);
    const float scale = (br ? scale_fp : scale_tp)[0];

    fused_s[t] = fused_ws[(size_t)b * (L_ * C_) + t];
    __syncthreads();
    {
        const int n = t >> 1, h = t & 1;
        float xv[64];
        const float4* xr = (const float4*)(xg + n * C_ + h * 64);
#pragma unroll
        for (int i4 = 0; i4 < 16; ++i4) {
            float4 u = xr[i4];
            xv[i4 * 4 + 0] = u.x; xv[i4 * 4 + 1] = u.y;
            xv[i4 * 4 + 2] = u.z; xv[i4 * 4 + 3] = u.w;
        }
        float s0 = 0, s1 = 0, s2 = 0, s3 = 0;
#pragma unroll
        for (int k = 0; k < 64; ++k) {
            int c = h * 64 + k; float x = xv[k];
            s0 += x * fused_s[c];          s1 += x * fused_s[C_ + c];
            s2 += x * fused_s[2 * C_ + c]; s3 += x * fused_s[3 * C_ + c];
        }
        s0 += __shfl_xor(s0, 1); s1 += __shfl_xor(s1, 1);
        s2 += __shfl_xor(s2, 1); s3 += __shfl_xor(s3, 1);
        const float isc = 0.0883883476483184f;
        s0 *= isc; s1 *= isc; s2 *= isc; s3 *= isc;
        float m = fmaxf(fmaxf(s0, s1), fmaxf(s2, s3));
        float p0 = __expf(s0 - m), p1 = __expf(s1 - m), p2 = __expf(s2 - m), p3 = __expf(s3 - m);
        float inv = scale / (p0 + p1 + p2 + p3);
        p0 *= inv; p1 *= inv; p2 *= inv; p3 *= inv;
#pragma unroll
        for (int ci = 0; ci < 8; ++ci) {
            unsigned short ov[8] __attribute__((aligned(16)));
#pragma unroll
            for (int i = 0; i < 8; ++i) {
                int k = ci * 8 + i; int c = h * 64 + k;
                float v = xv[k] + p0 * fused_s[c] + p1 * fused_s[C_ + c]
                        + p2 * fused_s[2 * C_ + c] + p3 * fused_s[3 * C_ + c];
                ov[i] = f2b(v);
            }
            int chunk = h * 8 + ci;
            *(uint4*)(smem + n * 256 + ((chunk * 16) ^ ((n & 7) << 4))) = *(const uint4*)ov;
        }
    }
    __syncthreads();

    const int w = t >> 6, lane = t & 63;
    const int lr = lane & 15, lq = lane >> 4;
    const int wrn = w >> 1, wcc = w & 1;
    const int wct = w >> 2, wnt = w & 3;
    const int rn  = w >> 1;

    f32x4 acc[4][4];
#pragma unroll
    for (int fm = 0; fm < 4; ++fm)
#pragma unroll
        for (int fn = 0; fn < 4; ++fn) acc[fm][fn] = f32x4{0.f, 0.f, 0.f, 0.f};
#pragma unroll
    for (int kk = 0; kk < 4; ++kk) {
        bf16x8 afr[4], bfr[4];
#pragma unroll
        for (int fm = 0; fm < 4; ++fm) {
            int n = wrn * 64 + fm * 16 + lr;
            afr[fm] = __builtin_bit_cast(bf16x8,
                *(const uint4*)(smem + n * 256 + ((kk * 64 + lq * 16) ^ ((n & 7) << 4))));
        }
#pragma unroll
        for (int fn = 0; fn < 4; ++fn) {
            int d = wcc * 64 + fn * 16 + lr;
            bfr[fn] = __builtin_bit_cast(bf16x8, *(const uint4*)(wt1 + d * C_ + kk * 32 + lq * 8));
        }
#pragma unroll
        for (int fm = 0; fm < 4; ++fm)
#pragma unroll
            for (int fn = 0; fn < 4; ++fn)
                acc[fm][fn] = __builtin_amdgcn_mfma_f32_16x16x32_bf16(afr[fm], bfr[fn], acc[fm][fn], 0, 0, 0);
    }
    for (int ch = 0; ch < 4; ++ch) {
        f32x4 acc2[4];
#pragma unroll
        for (int fn = 0; fn < 4; ++fn) acc2[fn] = f32x4{0.f, 0.f, 0.f, 0.f};
#pragma unroll
        for (int kk = 0; kk < 4; ++kk) {
            int n = ch * 64 + rn * 16 + lr;
            bf16x8 a = __builtin_bit_cast(bf16x8,
                *(const uint4*)(smem + n * 256 + ((kk * 64 + lq * 16) ^ ((n & 7) << 4))));
#pragma unroll
            for (int fn = 0; fn < 4; ++fn) {
                int d = wcc * 64 + fn * 16 + lr;
                bf16x8 bfr = __builtin_bit_cast(bf16x8, *(const uint4*)(wt2 + d * C_ + kk * 32 + lq * 8));
                acc2[fn] = __builtin_amdgcn_mfma_f32_16x16x32_bf16(a, bfr, acc2[fn], 0, 0, 0);
            }
        }
#pragma unroll
        for (int fn = 0; fn < 4; ++fn) {
            int c   = wcc * 64 + fn * 16 + lr;
            int n0l = rn * 16 + lq * 4;
            f32x4 a = acc2[fn];
            unsigned short tmp[4] __attribute__((aligned(8)));
#pragma unroll
            for (int r = 0; r < 4; ++r) tmp[r] = f2b(a[r]);
            *(uint2*)(cb + c * 128 + ((n0l * 2) ^ ((c & 7) << 4))) = *(const uint2*)tmp;
        }
        __syncthreads();
#pragma unroll
        for (int kk = 0; kk < 2; ++kk) {
            bf16x8 afr[4], bfr[4];
#pragma unroll
            for (int fm = 0; fm < 4; ++fm) {
                int n = wrn * 64 + fm * 16 + lr;
                afr[fm] = __builtin_bit_cast(bf16x8,
                    *(const uint4*)(adj + n * N_ + ch * 64 + kk * 32 + lq * 8));
            }
#pragma unroll
            for (int fn = 0; fn < 4; ++fn) {
                int c = wcc * 64 + fn * 16 + lr;
                bfr[fn] = __builtin_bit_cast(bf16x8,
                    *(const uint4*)(cb + c * 128 + ((kk * 64 + lq * 16) ^ ((c & 7) << 4))));
            }
#pragma unroll
            for (int fm = 0; fm < 4; ++fm)
#pragma unroll
                for (int fn = 0; fn < 4; ++fn)
                    acc[fm][fn] = __builtin_amdgcn_mfma_f32_16x16x32_bf16(afr[fm], bfr[fn], acc[fm][fn], 0, 0, 0);
        }
        __syncthreads();
    }
    uint2 Zb[4][4];
#pragma unroll
    for (int fm = 0; fm < 4; ++fm)
#pragma unroll
        for (int fn = 0; fn < 4; ++fn) {
            f32x4 a = acc[fm][fn];
            unsigned short tmp[4] __attribute__((aligned(8)));
#pragma unroll
            for (int r = 0; r < 4; ++r) tmp[r] = f2b(a[r]);
            Zb[fm][fn] = *(const uint2*)tmp;
        }
    f32x4 accO[4][4];
#pragma unroll
    for (int fm = 0; fm < 4; ++fm) {
        float4 b4 = *(const float4*)(bias + wct * 64 + fm * 16 + lq * 4);
#pragma unroll
        for (int fn = 0; fn < 4; ++fn) accO[fm][fn] = f32x4{b4.x, b4.y, b4.z, b4.w};
    }
#pragma unroll
    for (int kk = 0; kk < 4; ++kk) {
        bf16x8 afr[4], bfr[4];
#pragma unroll
        for (int fm = 0; fm < 4; ++fm) {
            int d = wct * 64 + fm * 16 + lr;
            afr[fm] = __builtin_bit_cast(bf16x8, *(const uint4*)(wt0 + d * C_ + kk * 32 + lq * 8));
        }
#pragma unroll
        for (int fn = 0; fn < 4; ++fn) {
            int n = wnt * 64 + fn * 16 + lr;
            bfr[fn] = __builtin_bit_cast(bf16x8,
                *(const uint4*)(smem + n * 256 + ((kk * 64 + lq * 16) ^ ((n & 7) << 4))));
        }
#pragma unroll
        for (int fm = 0; fm < 4; ++fm)
#pragma unroll
            for (int fn = 0; fn < 4; ++fn)
                accO[fm][fn] = __builtin_amdgcn_mfma_f32_16x16x32_bf16(afr[fm], bfr[fn], accO[fm][fn], 0, 0, 0);
    }
    for (int ch = 0; ch < 4; ++ch) {
        if (wrn == ch) {
#pragma unroll
            for (int fm = 0; fm < 4; ++fm)
#pragma unroll
                for (int fn = 0; fn < 4; ++fn) {
                    int c   = wcc * 64 + fn * 16 + lr;
                    int n0l = fm * 16 + lq * 4;
                    *(uint2*)(cb + c * 128 + ((n0l * 2) ^ ((c & 7) << 4))) = Zb[fm][fn];
                }
        }
        __syncthreads();
#pragma unroll
        for (int kk = 0; kk < 2; ++kk) {
            bf16x8 afr[4], bfr[4];
#pragma unroll
            for (int fm = 0; fm < 4; ++fm) {
                int c = wct * 64 + fm * 16 + lr;
                afr[fm] = __builtin_bit_cast(bf16x8,
                    *(const uint4*)(cb + c * 128 + ((kk * 64 + lq * 16) ^ ((c & 7) << 4))));
            }
#pragma unroll
            for (int fn = 0; fn < 4; ++fn) {
                int n = wnt * 64 + fn * 16 + lr;
                bfr[fn] = __builtin_bit_cast(bf16x8,
                    *(const uint4*)(adj + n * N_ + ch * 64 + kk * 32 + lq * 8));
            }
#pragma unroll
            for (int fm = 0; fm < 4; ++fm)
#pragma unroll
                for (int fn = 0; fn < 4; ++fn)
                    accO[fm][fn] = __builtin_amdgcn_mfma_f32_16x16x32_bf16(afr[fm], bfr[fn], accO[fm][fn], 0, 0, 0);
        }
        __syncthreads();
    }
#pragma unroll
    for (int fm = 0; fm < 4; ++fm) {
        int c0 = wct * 64 + fm * 16 + lq * 4;
#pragma unroll
        for (int fn = 0; fn < 4; ++fn) {
            int n = wnt * 64 + fn * 16 + lr;
            *(float4*)(og + n * C_ + c0) = __builtin_bit_cast(float4, accO[fm][fn]);
        }
    }
}

// ---------------------------------------------------------------------------
extern "C" void kernel_launch(void* const* d_in, const int* in_sizes, int n_in,
                              void* d_out, int out_size, void* d_ws, size_t ws_size,
                              hipStream_t stream)
{
    const float* timep = (const float*)d_in[0];
    const float* frep  = (const float*)d_in[1];
    const float* adjf  = (const float*)d_in[2];
    const float* lat   = (const float*)d_in[3];
    const float* sct   = (const float*)d_in[4];
    const float* scf   = (const float*)d_in[5];
    const float* Wt    = (const float*)d_in[6];
    const float* bt    = (const float*)d_in[7];
    const float* Wf    = (const float*)d_in[8];
    const float* bf    = (const float*)d_in[9];
    float* outp = (float*)d_out;

    float* fused_ws        = (float*)d_ws;                                        // 2 MB
    unsigned short* wtp    = (unsigned short*)((char*)d_ws + 2097152);            // 192 KB
    unsigned short* adj_bs = (unsigned short*)((char*)d_ws + 2097152 + 196608);   // 128 KB
    unsigned short* xpws   = (unsigned short*)((char*)d_ws + 4194304);            // 128 MB

    const size_t need = 4194304ull + 134217728ull;
    const int fast = (ws_size >= need) ? 1 : 0;

    hipFuncSetAttribute((const void*)k_latent,  hipFuncAttributeMaxDynamicSharedMemorySize, 145408);
    hipFuncSetAttribute((const void*)k_main_fb, hipFuncAttributeMaxDynamicSharedMemorySize, 81920);

    k_prep<<<640, 256, 0, stream>>>(Wt, Wf, adjf, wtp, adj_bs);
    k_latent<<<1024, 512, 145408, stream>>>(timep, frep, lat, sct, scf,
                                            fused_ws, xpws, fast);
    if (fast) {
        k_cheb<<<dim3(1024, 2), 512, 16384, stream>>>(adj_bs, wtp, bt, bf, xpws, outp);
    } else {
        k_main_fb<<<dim3(1024, 2), 512, 81920, stream>>>(timep, frep, adj_bs, fused_ws,
                                                         sct, scf, wtp, bt, bf, outp);
    }
}